// Round 8
// baseline (1822.952 us; speedup 1.0000x reference)
//
#include <hip/hip_runtime.h>

#define MTOT 131072   // b*n
#define NB   65536    // n per batch

typedef __attribute__((ext_vector_type(8))) __bf16 bf16x8;
typedef __attribute__((ext_vector_type(4))) float  f32x4;

// ---------------------------------------------------------------- pmin
__global__ void pmin_init_kernel(float* pmin){
    if (threadIdx.x < 6) pmin[threadIdx.x] = 2.0f;   // p in [0,1)
}

__global__ void pmin_kernel(const float* __restrict__ p, float* __restrict__ pmin){
    int bi = blockIdx.y;
    float m0 = 2.f, m1 = 2.f, m2 = 2.f;
    for (int ni = blockIdx.x * blockDim.x + threadIdx.x; ni < NB; ni += gridDim.x * blockDim.x){
        const float* pp = p + ((size_t)bi * NB + ni) * 3;
        m0 = fminf(m0, pp[0]); m1 = fminf(m1, pp[1]); m2 = fminf(m2, pp[2]);
    }
    #pragma unroll
    for (int o = 32; o > 0; o >>= 1){
        m0 = fminf(m0, __shfl_down(m0, o, 64));
        m1 = fminf(m1, __shfl_down(m1, o, 64));
        m2 = fminf(m2, __shfl_down(m2, o, 64));
    }
    if ((threadIdx.x & 63) == 0){
        atomicMin((int*)(pmin + bi*3 + 0), __float_as_int(m0));
        atomicMin((int*)(pmin + bi*3 + 1), __float_as_int(m1));
        atomicMin((int*)(pmin + bi*3 + 2), __float_as_int(m2));
    }
}

// ---------------------------------------------------------------- voxel scatter (atomicMax of ids)
// f64 voxelization (floor(p/g) in double) matches the numpy f64 reference bit-exactly.
template<int USE_LDS>
__global__ void scatter_kernel(const float* __restrict__ p, const float* __restrict__ pmin,
                               int* __restrict__ vgrid, int* __restrict__ gcbuf,
                               double gd, int D){
    extern __shared__ int lgrid[];
    int m  = blockIdx.x * blockDim.x + threadIdx.x;
    int bi = m >> 16;
    double px = (double)p[m*3], py = (double)p[m*3+1], pz = (double)p[m*3+2];
    int gx = (int)floor(px / gd) - (int)floor((double)pmin[bi*3+0] / gd);
    int gy = (int)floor(py / gd) - (int)floor((double)pmin[bi*3+1] / gd);
    int gz = (int)floor(pz / gd) - (int)floor((double)pmin[bi*3+2] / gd);
    gcbuf[m] = (gx << 20) | (gy << 10) | gz;
    int cell = (gx * D + gy) * D + gz;

    if (!USE_LDS){
        atomicMax(vgrid + bi * D * D * D + cell, m);
        return;
    }
    int ncell = D * D * D;
    for (int c = threadIdx.x; c < ncell; c += 256) lgrid[c] = -1;
    __syncthreads();
    atomicMax(&lgrid[cell], m);
    __syncthreads();
    int* vg = vgrid + bi * ncell;
    for (int c = threadIdx.x; c < ncell; c += 256){
        int v = lgrid[c];
        if (v >= 0) atomicMax(vg + c, v);
    }
}

// ---------------------------------------------------------------- 27-tap neighbor table
__global__ void nbr_kernel(const int* __restrict__ gcbuf, const int* __restrict__ vgrid,
                           int* __restrict__ nbr, int D){
    int m  = blockIdx.x * blockDim.x + threadIdx.x;
    int bi = m >> 16;
    int pk = gcbuf[m];
    int gx = pk >> 20, gy = (pk >> 10) & 1023, gz = pk & 1023;
    #pragma unroll
    for (int k = 0; k < 27; k++){
        int v;
        if (k == 13){
            v = m;
        } else {
            int x = gx + (k/9) - 1;
            int y = gy + ((k/3)%3) - 1;
            int z = gz + (k%3) - 1;
            if (x < 0 || y < 0 || z < 0 || x >= D || y >= D || z >= D) v = -1;
            else v = vgrid[((bi * D + x) * D + y) * D + z];
        }
        nbr[k * MTOT + m] = v;
    }
}

// ---------------------------------------------------------------- W -> transposed bf16 hi/lo planes
__global__ void wcv_kernel(const float* __restrict__ w_conv,
                           __bf16* __restrict__ wth, __bf16* __restrict__ wtl){
    int o = blockIdx.x * 256 + threadIdx.x;          // 442368 total
    int cv = o / 27648, r = o % 27648;
    int k = r / 1024, q = r % 1024, c = q / 32, j = q % 32;
    float x = w_conv[cv*27648 + k*1024 + j*32 + c];
    __bf16 hi = (__bf16)x;
    wth[o] = hi;
    wtl[o] = (__bf16)(x - (float)hi);
}

// ---------------------------------------------------------------- fused mlp1 + per-scale mlp -> bf16 hi/lo planes
__global__ void mlp_scale_kernel(const float* __restrict__ p, const float* __restrict__ w1,
                                 const float* __restrict__ b1,
                                 const float* __restrict__ w, const float* __restrict__ b,
                                 __bf16* __restrict__ h0h, __bf16* __restrict__ h0l){
    int t = blockIdx.x * blockDim.x + threadIdx.x;
    int c = t & 31, m = t >> 5;
    float x = p[m*3+0], y = p[m*3+1], z = p[m*3+2];
    float acc = b[c];
    #pragma unroll
    for (int j = 0; j < 32; j++){
        float ptsj = b1[j] + x * w1[j] + y * w1[32 + j] + z * w1[64 + j];
        acc += ptsj * w[j*32 + c];
    }
    __bf16 hi = (__bf16)acc;
    h0h[t] = hi;
    h0l[t] = (__bf16)(acc - (float)hi);
}

// ---------------------------------------------------------------- MFMA submanifold conv
// Wave = 16 points x 32 channels, 6 mfma_f32_16x16x32_bf16 per tap (3-term hi/lo).
// Block = 256 thr = 4 waves = 64 points; grid 2048 -> 8192 waves (100% occ ceiling;
// round-7 was capped at 50% by 32-pt waves and ran latency-bound at 41%).
// 2-stage tap pipeline: at tap k issue nbr id for k+2 + A-rows for k+1, MFMA tap k.
// Fragment maps (m89-verified): A row=lane&15,k=(lane>>4)*8+e; B col=lane&15,k same;
// D col=lane&15,row=(lane>>4)*4+reg.
// MODE 0: h1 planes = conv(f) + f
// MODE 1: out += (conv(f) + f + h0) @ w2i
// MODE 2: out  = b2 + (conv(f) + f + h0) @ w2i  (first scale)
template<int MODE>
__global__ __launch_bounds__(256, 8)
void conv_mfma_kernel(const __bf16* __restrict__ fh, const __bf16* __restrict__ fl,
                      const __bf16* __restrict__ wth, const __bf16* __restrict__ wtl,
                      const float* __restrict__ bias, const int* __restrict__ nbr,
                      const __bf16* __restrict__ r2h, const __bf16* __restrict__ r2l,
                      const float* __restrict__ w2i, const float* __restrict__ b2,
                      __bf16* __restrict__ outh, __bf16* __restrict__ outl,
                      float* __restrict__ out)
{
    __shared__ float vsh[64][33];
    int tid  = threadIdx.x;
    int lane = tid & 63, wid = tid >> 6;
    int col  = lane & 15, kq = lane >> 4;            // kq = k-chunk / row-group
    int ptA  = blockIdx.x * 64 + wid * 16 + col;
    const int fragoff = kq * 8;

    float bv0 = bias[col], bv1 = bias[col + 16];
    f32x4 acc0 = {bv0,bv0,bv0,bv0}, acc1 = {bv1,bv1,bv1,bv1};

    // pipeline prologue: tap0 rows + tap1 id in flight
    int nb_cur = nbr[ptA];
    int nb_nxt = nbr[MTOT + ptA];
    size_t oc = (size_t)(nb_cur < 0 ? 0 : nb_cur) * 32 + fragoff;
    bf16x8 ah = *(const bf16x8*)(fh + oc);
    bf16x8 al = *(const bf16x8*)(fl + oc);
    bool mcur = nb_cur < 0;

    #pragma unroll 1
    for (int k = 0; k < 27; k++){
        int nb_n2 = (k < 25) ? nbr[(k+2) * MTOT + ptA] : 0;          // id for k+2
        size_t on = (size_t)(nb_nxt < 0 ? 0 : nb_nxt) * 32 + fragoff; // rows for k+1
        bf16x8 ah_n = *(const bf16x8*)(fh + on);
        bf16x8 al_n = *(const bf16x8*)(fl + on);
        bool mnxt = nb_nxt < 0;

        const __bf16* wb = wth + (size_t)k*1024 + col*32 + fragoff;
        const __bf16* wc = wtl + (size_t)k*1024 + col*32 + fragoff;
        bf16x8 b0h = *(const bf16x8*)(wb);
        bf16x8 b1h = *(const bf16x8*)(wb + 512);     // col half 1
        bf16x8 b0l = *(const bf16x8*)(wc);
        bf16x8 b1l = *(const bf16x8*)(wc + 512);

        bf16x8 z = {};
        bf16x8 xh = mcur ? z : ah;
        bf16x8 xl = mcur ? z : al;

        acc0 = __builtin_amdgcn_mfma_f32_16x16x32_bf16(xh, b0h, acc0, 0,0,0);
        acc0 = __builtin_amdgcn_mfma_f32_16x16x32_bf16(xh, b0l, acc0, 0,0,0);
        acc0 = __builtin_amdgcn_mfma_f32_16x16x32_bf16(xl, b0h, acc0, 0,0,0);
        acc1 = __builtin_amdgcn_mfma_f32_16x16x32_bf16(xh, b1h, acc1, 0,0,0);
        acc1 = __builtin_amdgcn_mfma_f32_16x16x32_bf16(xh, b1l, acc1, 0,0,0);
        acc1 = __builtin_amdgcn_mfma_f32_16x16x32_bf16(xl, b1h, acc1, 0,0,0);

        ah = ah_n; al = al_n; mcur = mnxt; nb_nxt = nb_n2;
    }

    // stage D into LDS: row = wid*16 + kq*4 + r, col = half*16 + (lane&15)
    #pragma unroll
    for (int r = 0; r < 4; r++){
        vsh[wid*16 + kq*4 + r][col]      = acc0[r];
        vsh[wid*16 + kq*4 + r][col + 16] = acc1[r];
    }
    __syncthreads();

    if (MODE == 0){
        int eidx = tid * 8;                          // 256 thr x 8 = 64 pts x 32 ch
        int pt = eidx >> 5, c0 = eidx & 31;
        size_t g = (size_t)blockIdx.x * 2048 + eidx;
        bf16x8 rh = *(const bf16x8*)(fh + g);
        bf16x8 rl = *(const bf16x8*)(fl + g);
        bf16x8 oh8, ol8;
        #pragma unroll
        for (int j = 0; j < 8; j++){
            float v = vsh[pt][c0 + j] + (float)rh[j] + (float)rl[j];
            __bf16 hi = (__bf16)v;
            oh8[j] = hi;
            ol8[j] = (__bf16)(v - (float)hi);
        }
        *(bf16x8*)(outh + g) = oh8;
        *(bf16x8*)(outl + g) = ol8;
    } else {
        int eidx = tid * 8;
        int pt = eidx >> 5, c0 = eidx & 31;
        size_t g = (size_t)blockIdx.x * 2048 + eidx;
        bf16x8 rh = *(const bf16x8*)(fh + g);
        bf16x8 rl = *(const bf16x8*)(fl + g);
        bf16x8 sh = *(const bf16x8*)(r2h + g);
        bf16x8 sl = *(const bf16x8*)(r2l + g);
        #pragma unroll
        for (int j = 0; j < 8; j++)
            vsh[pt][c0 + j] += (float)rh[j] + (float)rl[j] + (float)sh[j] + (float)sl[j];
        __syncthreads();

        int pm = tid & 63;                           // point 0..63
        int tg = __builtin_amdgcn_readfirstlane(tid >> 6);   // out-slice, wave-uniform
        size_t m = (size_t)blockIdx.x * 64 + pm;
        float o32[32];
        float* obase = out + m*128 + tg*32;
        if (MODE == 2){
            #pragma unroll
            for (int o = 0; o < 32; o++) o32[o] = b2[tg*32 + o];
        } else {
            #pragma unroll
            for (int q = 0; q < 8; q++){
                float4 t4 = ((const float4*)obase)[q];
                o32[q*4+0] = t4.x; o32[q*4+1] = t4.y; o32[q*4+2] = t4.z; o32[q*4+3] = t4.w;
            }
        }
        #pragma unroll
        for (int c = 0; c < 32; c++){
            float vc = vsh[pm][c];
            const float* w2r = w2i + c*128 + tg*32;  // scalar base
            #pragma unroll
            for (int o = 0; o < 32; o++) o32[o] += vc * w2r[o];
        }
        #pragma unroll
        for (int q = 0; q < 8; q++)
            ((float4*)obase)[q] = make_float4(o32[q*4+0], o32[q*4+1], o32[q*4+2], o32[q*4+3]);
    }
}

// ---------------------------------------------------------------- launch
extern "C" void kernel_launch(void* const* d_in, const int* in_sizes, int n_in,
                              void* d_out, int out_size, void* d_ws, size_t ws_size,
                              hipStream_t stream)
{
    static const int want[9] = {393216, 96, 32, 8192, 256, 442368, 512, 32768, 128};
    const void* bound[9];
    for (int i = 0; i < 9; i++) bound[i] = d_in[i];
    if (n_in == 9){
        for (int i = 0; i < 9; i++)
            for (int j = 0; j < 9; j++)
                if (in_sizes[j] == want[i]) { bound[i] = d_in[j]; break; }
    }
    const float* p      = (const float*)bound[0];
    const float* w1     = (const float*)bound[1];
    const float* b1     = (const float*)bound[2];
    const float* w_mlp  = (const float*)bound[3];
    const float* b_mlp  = (const float*)bound[4];
    const float* w_conv = (const float*)bound[5];
    const float* b_conv = (const float*)bound[6];
    const float* w2     = (const float*)bound[7];
    const float* b2     = (const float*)bound[8];
    float* out = (float*)d_out;

    // Workspace (~49.5 MB): activation planes + nbr + W planes.
    // vgrid aliases h1h, gcbuf aliases h1l (lifetime-disjoint per scale).
    char* ws = (char*)d_ws;
    __bf16* h0h  = (__bf16*)(ws);
    __bf16* h0l  = (__bf16*)(ws + 8388608);
    __bf16* h1h  = (__bf16*)(ws + 16777216);
    int*    vgrid= (int*)   (ws + 16777216);            // alias of h1h
    __bf16* h1l  = (__bf16*)(ws + 25165824);
    int*    gcbuf= (int*)   (ws + 25165824);            // alias of h1l
    int*    nbr  = (int*)   (ws + 33554432);            // 14,155,776 B
    __bf16* wth  = (__bf16*)(ws + 47710208);            // 884,736 B
    __bf16* wtl  = (__bf16*)(ws + 48594944);            // 884,736 B
    float*  pmin = (float*) (ws + 49479680);

    static const double GS[8] = {0.01, 0.02, 0.04, 0.08, 0.16, 0.32, 0.64, 1.28};
    static const int    DS[8] = {101, 51, 26, 14, 8, 5, 3, 2};   // ceil(1/g)+1

    pmin_init_kernel<<<1, 64, 0, stream>>>(pmin);
    pmin_kernel<<<dim3(64, 2), 256, 0, stream>>>(p, pmin);
    wcv_kernel<<<1728, 256, 0, stream>>>(w_conv, wth, wtl);

    for (int i = 0; i < 8; i++){
        int D = DS[i]; double gd = GS[i];
        int ncell = D * D * D;
        hipMemsetAsync(vgrid, 0xFF, (size_t)2*ncell*sizeof(int), stream);
        if (ncell <= 2744)
            scatter_kernel<1><<<MTOT/256, 256, ncell*sizeof(int), stream>>>(p, pmin, vgrid, gcbuf, gd, D);
        else
            scatter_kernel<0><<<MTOT/256, 256, 0, stream>>>(p, pmin, vgrid, gcbuf, gd, D);
        nbr_kernel<<<MTOT/256, 256, 0, stream>>>(gcbuf, vgrid, nbr, D);
        mlp_scale_kernel<<<(MTOT*32)/256, 256, 0, stream>>>(p, w1, b1, w_mlp + i*1024, b_mlp + i*32, h0h, h0l);

        conv_mfma_kernel<0><<<MTOT/64, 256, 0, stream>>>(
            h0h, h0l, wth + (size_t)(2*i)*27648, wtl + (size_t)(2*i)*27648,
            b_conv + (2*i)*32, nbr, nullptr, nullptr, nullptr, nullptr,
            h1h, h1l, nullptr);

        if (i == 0)
            conv_mfma_kernel<2><<<MTOT/64, 256, 0, stream>>>(
                h1h, h1l, wth + (size_t)(2*i+1)*27648, wtl + (size_t)(2*i+1)*27648,
                b_conv + (2*i+1)*32, nbr, h0h, h0l, w2 + i*32*128, b2,
                nullptr, nullptr, out);
        else
            conv_mfma_kernel<1><<<MTOT/64, 256, 0, stream>>>(
                h1h, h1l, wth + (size_t)(2*i+1)*27648, wtl + (size_t)(2*i+1)*27648,
                b_conv + (2*i+1)*32, nbr, h0h, h0l, w2 + i*32*128, nullptr,
                nullptr, nullptr, out);
    }
}

// Round 9
// 1562.353 us; speedup vs baseline: 1.1668x; 1.1668x over previous
//
#include <hip/hip_runtime.h>

#define MTOT 131072   // b*n
#define NB   65536    // n per batch

typedef __attribute__((ext_vector_type(8))) __bf16 bf16x8;
typedef __attribute__((ext_vector_type(4))) float  f32x4;

// ---------------------------------------------------------------- pmin
__global__ void pmin_init_kernel(float* pmin){
    if (threadIdx.x < 6) pmin[threadIdx.x] = 2.0f;   // p in [0,1)
}

__global__ void pmin_kernel(const float* __restrict__ p, float* __restrict__ pmin){
    int bi = blockIdx.y;
    float m0 = 2.f, m1 = 2.f, m2 = 2.f;
    for (int ni = blockIdx.x * blockDim.x + threadIdx.x; ni < NB; ni += gridDim.x * blockDim.x){
        const float* pp = p + ((size_t)bi * NB + ni) * 3;
        m0 = fminf(m0, pp[0]); m1 = fminf(m1, pp[1]); m2 = fminf(m2, pp[2]);
    }
    #pragma unroll
    for (int o = 32; o > 0; o >>= 1){
        m0 = fminf(m0, __shfl_down(m0, o, 64));
        m1 = fminf(m1, __shfl_down(m1, o, 64));
        m2 = fminf(m2, __shfl_down(m2, o, 64));
    }
    if ((threadIdx.x & 63) == 0){
        atomicMin((int*)(pmin + bi*3 + 0), __float_as_int(m0));
        atomicMin((int*)(pmin + bi*3 + 1), __float_as_int(m1));
        atomicMin((int*)(pmin + bi*3 + 2), __float_as_int(m2));
    }
}

// ---------------------------------------------------------------- voxel scatter (atomicMax of ids)
// f64 voxelization (floor(p/g) in double) matches the numpy f64 reference bit-exactly.
template<int USE_LDS>
__global__ void scatter_kernel(const float* __restrict__ p, const float* __restrict__ pmin,
                               int* __restrict__ vgrid, int* __restrict__ gcbuf,
                               double gd, int D){
    extern __shared__ int lgrid[];
    int m  = blockIdx.x * blockDim.x + threadIdx.x;
    int bi = m >> 16;
    double px = (double)p[m*3], py = (double)p[m*3+1], pz = (double)p[m*3+2];
    int gx = (int)floor(px / gd) - (int)floor((double)pmin[bi*3+0] / gd);
    int gy = (int)floor(py / gd) - (int)floor((double)pmin[bi*3+1] / gd);
    int gz = (int)floor(pz / gd) - (int)floor((double)pmin[bi*3+2] / gd);
    gcbuf[m] = (gx << 20) | (gy << 10) | gz;
    int cell = (gx * D + gy) * D + gz;

    if (!USE_LDS){
        atomicMax(vgrid + bi * D * D * D + cell, m);
        return;
    }
    int ncell = D * D * D;
    for (int c = threadIdx.x; c < ncell; c += 256) lgrid[c] = -1;
    __syncthreads();
    atomicMax(&lgrid[cell], m);
    __syncthreads();
    int* vg = vgrid + bi * ncell;
    for (int c = threadIdx.x; c < ncell; c += 256){
        int v = lgrid[c];
        if (v >= 0) atomicMax(vg + c, v);
    }
}

// ---------------------------------------------------------------- 27-tap neighbor table
__global__ void nbr_kernel(const int* __restrict__ gcbuf, const int* __restrict__ vgrid,
                           int* __restrict__ nbr, int D){
    int m  = blockIdx.x * blockDim.x + threadIdx.x;
    int bi = m >> 16;
    int pk = gcbuf[m];
    int gx = pk >> 20, gy = (pk >> 10) & 1023, gz = pk & 1023;
    #pragma unroll
    for (int k = 0; k < 27; k++){
        int v;
        if (k == 13){
            v = m;
        } else {
            int x = gx + (k/9) - 1;
            int y = gy + ((k/3)%3) - 1;
            int z = gz + (k%3) - 1;
            if (x < 0 || y < 0 || z < 0 || x >= D || y >= D || z >= D) v = -1;
            else v = vgrid[((bi * D + x) * D + y) * D + z];
        }
        nbr[k * MTOT + m] = v;
    }
}

// ---------------------------------------------------------------- W -> transposed bf16 hi/lo planes
__global__ void wcv_kernel(const float* __restrict__ w_conv,
                           __bf16* __restrict__ wth, __bf16* __restrict__ wtl){
    int o = blockIdx.x * 256 + threadIdx.x;          // 442368 total
    int cv = o / 27648, r = o % 27648;
    int k = r / 1024, q = r % 1024, c = q / 32, j = q % 32;
    float x = w_conv[cv*27648 + k*1024 + j*32 + c];
    __bf16 hi = (__bf16)x;
    wth[o] = hi;
    wtl[o] = (__bf16)(x - (float)hi);
}

// ---------------------------------------------------------------- fused mlp1 + per-scale mlp -> bf16 hi/lo planes
__global__ void mlp_scale_kernel(const float* __restrict__ p, const float* __restrict__ w1,
                                 const float* __restrict__ b1,
                                 const float* __restrict__ w, const float* __restrict__ b,
                                 __bf16* __restrict__ h0h, __bf16* __restrict__ h0l){
    int t = blockIdx.x * blockDim.x + threadIdx.x;
    int c = t & 31, m = t >> 5;
    float x = p[m*3+0], y = p[m*3+1], z = p[m*3+2];
    float acc = b[c];
    #pragma unroll
    for (int j = 0; j < 32; j++){
        float ptsj = b1[j] + x * w1[j] + y * w1[32 + j] + z * w1[64 + j];
        acc += ptsj * w[j*32 + c];
    }
    __bf16 hi = (__bf16)acc;
    h0h[t] = hi;
    h0l[t] = (__bf16)(acc - (float)hi);
}

// ---------------------------------------------------------------- MFMA submanifold conv, 2-way TAP split
// Round-7 per-wave structure (32 pts/wave, 12 MFMA + 4 A-loads + 4 W-loads + 2 nbr
// per tap — the efficient VMEM:MFMA ratio) but taps split across 2 waves:
// half 0 = taps 0..13 (center+bias), half 1 = taps 14..26. Waves double to 8192
// -> occupancy ceiling 100% (round 7 capped at 50%, ran 41% latency-bound).
// Round-8 lesson baked in: NO launch-bounds VGPR cap (spills), no deep A-pipeline.
// Half-1 dumps acc to LDS; half-0 adds -> same epilogues as round 7.
// Fragment maps (m89-verified): A row=lane&15,k=(lane>>4)*8+e; B col=lane&15;
// D col=lane&15,row=(lane>>4)*4+reg.
// MODE 0: h1 planes = conv(f) + f
// MODE 1: out += (conv(f) + f + h0) @ w2i
// MODE 2: out  = b2 + (conv(f) + f + h0) @ w2i  (first scale)
template<int MODE>
__global__ __launch_bounds__(256)
void conv_mfma_kernel(const __bf16* __restrict__ fh, const __bf16* __restrict__ fl,
                      const __bf16* __restrict__ wth, const __bf16* __restrict__ wtl,
                      const float* __restrict__ bias, const int* __restrict__ nbr,
                      const __bf16* __restrict__ r2h, const __bf16* __restrict__ r2l,
                      const float* __restrict__ w2i, const float* __restrict__ b2,
                      __bf16* __restrict__ outh, __bf16* __restrict__ outl,
                      float* __restrict__ out)
{
    __shared__ float vsh[64][33];
    int tid  = threadIdx.x;
    int lane = tid & 63, wid = tid >> 6;
    int pair = wid >> 1;                             // point-group 0/1 (32 pts each)
    int half = wid & 1;                              // tap half
    int col  = lane & 15, kq = lane >> 4;
    int m0   = blockIdx.x * 64 + pair * 32;
    int ptA  = m0 + col, ptB = ptA + 16;
    const int fragoff = kq * 8;

    f32x4 acc00, acc01, acc10, acc11;
    if (half == 0){
        float bv0 = bias[col], bv1 = bias[col + 16];
        acc00 = (f32x4){bv0,bv0,bv0,bv0}; acc01 = (f32x4){bv1,bv1,bv1,bv1};
        acc10 = (f32x4){bv0,bv0,bv0,bv0}; acc11 = (f32x4){bv1,bv1,bv1,bv1};
    } else {
        acc00 = (f32x4){0,0,0,0}; acc01 = (f32x4){0,0,0,0};
        acc10 = (f32x4){0,0,0,0}; acc11 = (f32x4){0,0,0,0};
    }

    int k0 = half ? 14 : 0;
    int k1 = half ? 27 : 14;
    #pragma unroll 1
    for (int k = k0; k < k1; k++){
        int nb0 = nbr[k * MTOT + ptA];
        int nb1 = nbr[k * MTOT + ptB];
        size_t o0 = (size_t)(nb0 < 0 ? 0 : nb0) * 32 + fragoff;
        size_t o1 = (size_t)(nb1 < 0 ? 0 : nb1) * 32 + fragoff;
        bf16x8 a0h = *(const bf16x8*)(fh + o0);
        bf16x8 a0l = *(const bf16x8*)(fl + o0);
        bf16x8 a1h = *(const bf16x8*)(fh + o1);
        bf16x8 a1l = *(const bf16x8*)(fl + o1);
        bf16x8 z = {};
        if (nb0 < 0){ a0h = z; a0l = z; }
        if (nb1 < 0){ a1h = z; a1l = z; }

        const __bf16* wb = wth + (size_t)k*1024 + col*32 + fragoff;
        const __bf16* wc = wtl + (size_t)k*1024 + col*32 + fragoff;
        bf16x8 b0h = *(const bf16x8*)(wb);
        bf16x8 b1h = *(const bf16x8*)(wb + 512);     // col half 1 (+16 cols * 32)
        bf16x8 b0l = *(const bf16x8*)(wc);
        bf16x8 b1l = *(const bf16x8*)(wc + 512);

        acc00 = __builtin_amdgcn_mfma_f32_16x16x32_bf16(a0h, b0h, acc00, 0,0,0);
        acc00 = __builtin_amdgcn_mfma_f32_16x16x32_bf16(a0h, b0l, acc00, 0,0,0);
        acc00 = __builtin_amdgcn_mfma_f32_16x16x32_bf16(a0l, b0h, acc00, 0,0,0);
        acc01 = __builtin_amdgcn_mfma_f32_16x16x32_bf16(a0h, b1h, acc01, 0,0,0);
        acc01 = __builtin_amdgcn_mfma_f32_16x16x32_bf16(a0h, b1l, acc01, 0,0,0);
        acc01 = __builtin_amdgcn_mfma_f32_16x16x32_bf16(a0l, b1h, acc01, 0,0,0);
        acc10 = __builtin_amdgcn_mfma_f32_16x16x32_bf16(a1h, b0h, acc10, 0,0,0);
        acc10 = __builtin_amdgcn_mfma_f32_16x16x32_bf16(a1h, b0l, acc10, 0,0,0);
        acc10 = __builtin_amdgcn_mfma_f32_16x16x32_bf16(a1l, b0h, acc10, 0,0,0);
        acc11 = __builtin_amdgcn_mfma_f32_16x16x32_bf16(a1h, b1h, acc11, 0,0,0);
        acc11 = __builtin_amdgcn_mfma_f32_16x16x32_bf16(a1h, b1l, acc11, 0,0,0);
        acc11 = __builtin_amdgcn_mfma_f32_16x16x32_bf16(a1l, b1h, acc11, 0,0,0);
    }

    // ---- combine tap halves in LDS ----
    // D rows: pair*32 + rb*16 + kq*4 + r, cols: ch*16 + col
    if (half == 1){
        #pragma unroll
        for (int r = 0; r < 4; r++){
            vsh[pair*32 + kq*4 + r][col]           = acc00[r];
            vsh[pair*32 + kq*4 + r][col + 16]      = acc01[r];
            vsh[pair*32 + 16 + kq*4 + r][col]      = acc10[r];
            vsh[pair*32 + 16 + kq*4 + r][col + 16] = acc11[r];
        }
    }
    __syncthreads();
    if (half == 0){
        #pragma unroll
        for (int r = 0; r < 4; r++){
            vsh[pair*32 + kq*4 + r][col]           += acc00[r];
            vsh[pair*32 + kq*4 + r][col + 16]      += acc01[r];
            vsh[pair*32 + 16 + kq*4 + r][col]      += acc10[r];
            vsh[pair*32 + 16 + kq*4 + r][col + 16] += acc11[r];
        }
    }
    __syncthreads();

    if (MODE == 0){
        int eidx = tid * 8;                          // 64 pts x 32 ch = 2048 = 256 x 8
        int pt = eidx >> 5, c0 = eidx & 31;
        size_t g = (size_t)blockIdx.x * 2048 + eidx;
        bf16x8 rh = *(const bf16x8*)(fh + g);
        bf16x8 rl = *(const bf16x8*)(fl + g);
        bf16x8 oh8, ol8;
        #pragma unroll
        for (int j = 0; j < 8; j++){
            float v = vsh[pt][c0 + j] + (float)rh[j] + (float)rl[j];
            __bf16 hi = (__bf16)v;
            oh8[j] = hi;
            ol8[j] = (__bf16)(v - (float)hi);
        }
        *(bf16x8*)(outh + g) = oh8;
        *(bf16x8*)(outl + g) = ol8;
    } else {
        int eidx = tid * 8;
        int pt = eidx >> 5, c0 = eidx & 31;
        size_t g = (size_t)blockIdx.x * 2048 + eidx;
        bf16x8 rh = *(const bf16x8*)(fh + g);
        bf16x8 rl = *(const bf16x8*)(fl + g);
        bf16x8 sh = *(const bf16x8*)(r2h + g);
        bf16x8 sl = *(const bf16x8*)(r2l + g);
        #pragma unroll
        for (int j = 0; j < 8; j++)
            vsh[pt][c0 + j] += (float)rh[j] + (float)rl[j] + (float)sh[j] + (float)sl[j];
        __syncthreads();

        int pm = tid & 63;                           // point 0..63
        int tg = __builtin_amdgcn_readfirstlane(tid >> 6);   // out-slice, wave-uniform
        size_t m = (size_t)blockIdx.x * 64 + pm;
        float o32[32];
        float* obase = out + m*128 + tg*32;
        if (MODE == 2){
            #pragma unroll
            for (int o = 0; o < 32; o++) o32[o] = b2[tg*32 + o];
        } else {
            #pragma unroll
            for (int q = 0; q < 8; q++){
                float4 t4 = ((const float4*)obase)[q];
                o32[q*4+0] = t4.x; o32[q*4+1] = t4.y; o32[q*4+2] = t4.z; o32[q*4+3] = t4.w;
            }
        }
        #pragma unroll
        for (int c = 0; c < 32; c++){
            float vc = vsh[pm][c];
            const float* w2r = w2i + c*128 + tg*32;  // scalar base
            #pragma unroll
            for (int o = 0; o < 32; o++) o32[o] += vc * w2r[o];
        }
        #pragma unroll
        for (int q = 0; q < 8; q++)
            ((float4*)obase)[q] = make_float4(o32[q*4+0], o32[q*4+1], o32[q*4+2], o32[q*4+3]);
    }
}

// ---------------------------------------------------------------- launch
extern "C" void kernel_launch(void* const* d_in, const int* in_sizes, int n_in,
                              void* d_out, int out_size, void* d_ws, size_t ws_size,
                              hipStream_t stream)
{
    static const int want[9] = {393216, 96, 32, 8192, 256, 442368, 512, 32768, 128};
    const void* bound[9];
    for (int i = 0; i < 9; i++) bound[i] = d_in[i];
    if (n_in == 9){
        for (int i = 0; i < 9; i++)
            for (int j = 0; j < 9; j++)
                if (in_sizes[j] == want[i]) { bound[i] = d_in[j]; break; }
    }
    const float* p      = (const float*)bound[0];
    const float* w1     = (const float*)bound[1];
    const float* b1     = (const float*)bound[2];
    const float* w_mlp  = (const float*)bound[3];
    const float* b_mlp  = (const float*)bound[4];
    const float* w_conv = (const float*)bound[5];
    const float* b_conv = (const float*)bound[6];
    const float* w2     = (const float*)bound[7];
    const float* b2     = (const float*)bound[8];
    float* out = (float*)d_out;

    // Workspace (~49.5 MB): activation planes + nbr + W planes.
    // vgrid aliases h1h, gcbuf aliases h1l (lifetime-disjoint per scale).
    char* ws = (char*)d_ws;
    __bf16* h0h  = (__bf16*)(ws);
    __bf16* h0l  = (__bf16*)(ws + 8388608);
    __bf16* h1h  = (__bf16*)(ws + 16777216);
    int*    vgrid= (int*)   (ws + 16777216);            // alias of h1h
    __bf16* h1l  = (__bf16*)(ws + 25165824);
    int*    gcbuf= (int*)   (ws + 25165824);            // alias of h1l
    int*    nbr  = (int*)   (ws + 33554432);            // 14,155,776 B
    __bf16* wth  = (__bf16*)(ws + 47710208);            // 884,736 B
    __bf16* wtl  = (__bf16*)(ws + 48594944);            // 884,736 B
    float*  pmin = (float*) (ws + 49479680);

    static const double GS[8] = {0.01, 0.02, 0.04, 0.08, 0.16, 0.32, 0.64, 1.28};
    static const int    DS[8] = {101, 51, 26, 14, 8, 5, 3, 2};   // ceil(1/g)+1

    pmin_init_kernel<<<1, 64, 0, stream>>>(pmin);
    pmin_kernel<<<dim3(64, 2), 256, 0, stream>>>(p, pmin);
    wcv_kernel<<<1728, 256, 0, stream>>>(w_conv, wth, wtl);

    for (int i = 0; i < 8; i++){
        int D = DS[i]; double gd = GS[i];
        int ncell = D * D * D;
        hipMemsetAsync(vgrid, 0xFF, (size_t)2*ncell*sizeof(int), stream);
        if (ncell <= 2744)
            scatter_kernel<1><<<MTOT/256, 256, ncell*sizeof(int), stream>>>(p, pmin, vgrid, gcbuf, gd, D);
        else
            scatter_kernel<0><<<MTOT/256, 256, 0, stream>>>(p, pmin, vgrid, gcbuf, gd, D);
        nbr_kernel<<<MTOT/256, 256, 0, stream>>>(gcbuf, vgrid, nbr, D);
        mlp_scale_kernel<<<(MTOT*32)/256, 256, 0, stream>>>(p, w1, b1, w_mlp + i*1024, b_mlp + i*32, h0h, h0l);

        conv_mfma_kernel<0><<<MTOT/64, 256, 0, stream>>>(
            h0h, h0l, wth + (size_t)(2*i)*27648, wtl + (size_t)(2*i)*27648,
            b_conv + (2*i)*32, nbr, nullptr, nullptr, nullptr, nullptr,
            h1h, h1l, nullptr);

        if (i == 0)
            conv_mfma_kernel<2><<<MTOT/64, 256, 0, stream>>>(
                h1h, h1l, wth + (size_t)(2*i+1)*27648, wtl + (size_t)(2*i+1)*27648,
                b_conv + (2*i+1)*32, nbr, h0h, h0l, w2 + i*32*128, b2,
                nullptr, nullptr, out);
        else
            conv_mfma_kernel<1><<<MTOT/64, 256, 0, stream>>>(
                h1h, h1l, wth + (size_t)(2*i+1)*27648, wtl + (size_t)(2*i+1)*27648,
                b_conv + (2*i+1)*32, nbr, h0h, h0l, w2 + i*32*128, nullptr,
                nullptr, nullptr, out);
    }
}

// Round 10
// 1347.766 us; speedup vs baseline: 1.3526x; 1.1592x over previous
//
#include <hip/hip_runtime.h>

#define MTOT 131072   // b*n
#define NB   65536    // n per batch

typedef __attribute__((ext_vector_type(8))) __bf16 bf16x8;
typedef __attribute__((ext_vector_type(4))) __bf16 bf16x4;
typedef __attribute__((ext_vector_type(4))) float  f32x4;

// ---------------------------------------------------------------- pmin
__global__ void pmin_init_kernel(float* pmin){
    if (threadIdx.x < 6) pmin[threadIdx.x] = 2.0f;   // p in [0,1)
}

__global__ void pmin_kernel(const float* __restrict__ p, float* __restrict__ pmin){
    int bi = blockIdx.y;
    float m0 = 2.f, m1 = 2.f, m2 = 2.f;
    for (int ni = blockIdx.x * blockDim.x + threadIdx.x; ni < NB; ni += gridDim.x * blockDim.x){
        const float* pp = p + ((size_t)bi * NB + ni) * 3;
        m0 = fminf(m0, pp[0]); m1 = fminf(m1, pp[1]); m2 = fminf(m2, pp[2]);
    }
    #pragma unroll
    for (int o = 32; o > 0; o >>= 1){
        m0 = fminf(m0, __shfl_down(m0, o, 64));
        m1 = fminf(m1, __shfl_down(m1, o, 64));
        m2 = fminf(m2, __shfl_down(m2, o, 64));
    }
    if ((threadIdx.x & 63) == 0){
        atomicMin((int*)(pmin + bi*3 + 0), __float_as_int(m0));
        atomicMin((int*)(pmin + bi*3 + 1), __float_as_int(m1));
        atomicMin((int*)(pmin + bi*3 + 2), __float_as_int(m2));
    }
}

// ---------------------------------------------------------------- voxel scatter (atomicMax of ids)
// f64 voxelization (floor(p/g) in double) matches the numpy f64 reference bit-exactly.
template<int USE_LDS>
__global__ void scatter_kernel(const float* __restrict__ p, const float* __restrict__ pmin,
                               int* __restrict__ vgrid, int* __restrict__ gcbuf,
                               double gd, int D){
    extern __shared__ int lgrid[];
    int m  = blockIdx.x * blockDim.x + threadIdx.x;
    int bi = m >> 16;
    double px = (double)p[m*3], py = (double)p[m*3+1], pz = (double)p[m*3+2];
    int gx = (int)floor(px / gd) - (int)floor((double)pmin[bi*3+0] / gd);
    int gy = (int)floor(py / gd) - (int)floor((double)pmin[bi*3+1] / gd);
    int gz = (int)floor(pz / gd) - (int)floor((double)pmin[bi*3+2] / gd);
    gcbuf[m] = (gx << 20) | (gy << 10) | gz;
    int cell = (gx * D + gy) * D + gz;

    if (!USE_LDS){
        atomicMax(vgrid + bi * D * D * D + cell, m);
        return;
    }
    int ncell = D * D * D;
    for (int c = threadIdx.x; c < ncell; c += 256) lgrid[c] = -1;
    __syncthreads();
    atomicMax(&lgrid[cell], m);
    __syncthreads();
    int* vg = vgrid + bi * ncell;
    for (int c = threadIdx.x; c < ncell; c += 256){
        int v = lgrid[c];
        if (v >= 0) atomicMax(vg + c, v);
    }
}

// ---------------------------------------------------------------- 27-tap neighbor table
__global__ void nbr_kernel(const int* __restrict__ gcbuf, const int* __restrict__ vgrid,
                           int* __restrict__ nbr, int D){
    int m  = blockIdx.x * blockDim.x + threadIdx.x;
    int bi = m >> 16;
    int pk = gcbuf[m];
    int gx = pk >> 20, gy = (pk >> 10) & 1023, gz = pk & 1023;
    #pragma unroll
    for (int k = 0; k < 27; k++){
        int v;
        if (k == 13){
            v = m;
        } else {
            int x = gx + (k/9) - 1;
            int y = gy + ((k/3)%3) - 1;
            int z = gz + (k%3) - 1;
            if (x < 0 || y < 0 || z < 0 || x >= D || y >= D || z >= D) v = -1;
            else v = vgrid[((bi * D + x) * D + y) * D + z];
        }
        nbr[k * MTOT + m] = v;
    }
}

// ---------------------------------------------------------------- W_conv -> transposed bf16 hi/lo planes
__global__ void wcv_kernel(const float* __restrict__ w_conv,
                           __bf16* __restrict__ wth, __bf16* __restrict__ wtl){
    int o = blockIdx.x * 256 + threadIdx.x;          // 442368 total
    int cv = o / 27648, r = o % 27648;
    int k = r / 1024, q = r % 1024, c = q / 32, j = q % 32;
    float x = w_conv[cv*27648 + k*1024 + j*32 + c];
    __bf16 hi = (__bf16)x;
    wth[o] = hi;
    wtl[o] = (__bf16)(x - (float)hi);
}

// ---------------------------------------------------------------- w2 -> [kc][c(128)][j(32)] bf16 hi/lo
__global__ void w2t_kernel(const float* __restrict__ w2,
                           __bf16* __restrict__ w2th, __bf16* __restrict__ w2tl){
    int o = blockIdx.x * 256 + threadIdx.x;          // 32768 total
    int kc = o >> 12, r = o & 4095, c = r >> 5, j = r & 31;
    float x = w2[(kc*32 + j)*128 + c];
    __bf16 hi = (__bf16)x;
    w2th[o] = hi;
    w2tl[o] = (__bf16)(x - (float)hi);
}

// ---------------------------------------------------------------- fused mlp1 + per-scale mlp -> bf16 hi/lo planes
__global__ void mlp_scale_kernel(const float* __restrict__ p, const float* __restrict__ w1,
                                 const float* __restrict__ b1,
                                 const float* __restrict__ w, const float* __restrict__ b,
                                 __bf16* __restrict__ h0h, __bf16* __restrict__ h0l){
    int t = blockIdx.x * blockDim.x + threadIdx.x;
    int c = t & 31, m = t >> 5;
    float x = p[m*3+0], y = p[m*3+1], z = p[m*3+2];
    float acc = b[c];
    #pragma unroll
    for (int j = 0; j < 32; j++){
        float ptsj = b1[j] + x * w1[j] + y * w1[32 + j] + z * w1[64 + j];
        acc += ptsj * w[j*32 + c];
    }
    __bf16 hi = (__bf16)acc;
    h0h[t] = hi;
    h0l[t] = (__bf16)(acc - (float)hi);
}

// ================================================================ BIG-WS PATH
// conv4: 4-way tap split. Block = 32 points x 4 waves (wave w = taps 7w..min(7w+7,27)).
// 4096 blocks x 4 waves = 16384 waves = 2x chip capacity -> packing slack (r9's
// exactly-8192 left occupancy at 50%). Per-wave structure identical to r9 (32 pts,
// 12 MFMA + 4 A + 4 W + 2 nbr per tap). Tree combine in LDS.
// MODE 0: h1 planes = conv(f) + f
// MODE 1: v planes  = conv(f) + f + h0      (w2 GEMM deferred to mlp2_kernel)
template<int MODE>
__global__ __launch_bounds__(256)
void conv4_kernel(const __bf16* __restrict__ fh, const __bf16* __restrict__ fl,
                  const __bf16* __restrict__ wth, const __bf16* __restrict__ wtl,
                  const float* __restrict__ bias, const int* __restrict__ nbr,
                  const __bf16* __restrict__ r2h, const __bf16* __restrict__ r2l,
                  __bf16* __restrict__ outh, __bf16* __restrict__ outl)
{
    __shared__ float buf0[32][33], buf1[32][33];
    int tid  = threadIdx.x;
    int lane = tid & 63, w = tid >> 6;
    int col  = lane & 15, kq = lane >> 4;
    int ptA  = blockIdx.x * 32 + col, ptB = ptA + 16;
    const int fragoff = kq * 8;

    f32x4 acc00, acc01, acc10, acc11;
    if (w == 0){
        float bv0 = bias[col], bv1 = bias[col + 16];
        acc00 = (f32x4){bv0,bv0,bv0,bv0}; acc01 = (f32x4){bv1,bv1,bv1,bv1};
        acc10 = (f32x4){bv0,bv0,bv0,bv0}; acc11 = (f32x4){bv1,bv1,bv1,bv1};
    } else {
        acc00 = (f32x4){0,0,0,0}; acc01 = (f32x4){0,0,0,0};
        acc10 = (f32x4){0,0,0,0}; acc11 = (f32x4){0,0,0,0};
    }

    int k0 = w * 7, k1 = (k0 + 7 < 27) ? k0 + 7 : 27;
    #pragma unroll 1
    for (int k = k0; k < k1; k++){
        int nb0 = nbr[k * MTOT + ptA];
        int nb1 = nbr[k * MTOT + ptB];
        size_t o0 = (size_t)(nb0 < 0 ? 0 : nb0) * 32 + fragoff;
        size_t o1 = (size_t)(nb1 < 0 ? 0 : nb1) * 32 + fragoff;
        bf16x8 a0h = *(const bf16x8*)(fh + o0);
        bf16x8 a0l = *(const bf16x8*)(fl + o0);
        bf16x8 a1h = *(const bf16x8*)(fh + o1);
        bf16x8 a1l = *(const bf16x8*)(fl + o1);
        bf16x8 z = {};
        if (nb0 < 0){ a0h = z; a0l = z; }
        if (nb1 < 0){ a1h = z; a1l = z; }

        const __bf16* wb = wth + (size_t)k*1024 + col*32 + fragoff;
        const __bf16* wc = wtl + (size_t)k*1024 + col*32 + fragoff;
        bf16x8 b0h = *(const bf16x8*)(wb);
        bf16x8 b1h = *(const bf16x8*)(wb + 512);
        bf16x8 b0l = *(const bf16x8*)(wc);
        bf16x8 b1l = *(const bf16x8*)(wc + 512);

        acc00 = __builtin_amdgcn_mfma_f32_16x16x32_bf16(a0h, b0h, acc00, 0,0,0);
        acc00 = __builtin_amdgcn_mfma_f32_16x16x32_bf16(a0h, b0l, acc00, 0,0,0);
        acc00 = __builtin_amdgcn_mfma_f32_16x16x32_bf16(a0l, b0h, acc00, 0,0,0);
        acc01 = __builtin_amdgcn_mfma_f32_16x16x32_bf16(a0h, b1h, acc01, 0,0,0);
        acc01 = __builtin_amdgcn_mfma_f32_16x16x32_bf16(a0h, b1l, acc01, 0,0,0);
        acc01 = __builtin_amdgcn_mfma_f32_16x16x32_bf16(a0l, b1h, acc01, 0,0,0);
        acc10 = __builtin_amdgcn_mfma_f32_16x16x32_bf16(a1h, b0h, acc10, 0,0,0);
        acc10 = __builtin_amdgcn_mfma_f32_16x16x32_bf16(a1h, b0l, acc10, 0,0,0);
        acc10 = __builtin_amdgcn_mfma_f32_16x16x32_bf16(a1l, b0h, acc10, 0,0,0);
        acc11 = __builtin_amdgcn_mfma_f32_16x16x32_bf16(a1h, b1h, acc11, 0,0,0);
        acc11 = __builtin_amdgcn_mfma_f32_16x16x32_bf16(a1h, b1l, acc11, 0,0,0);
        acc11 = __builtin_amdgcn_mfma_f32_16x16x32_bf16(a1l, b1h, acc11, 0,0,0);
    }

    // tree combine: final = (bias+T0+T2) + (T1+T3)
    if (w == 2){
        #pragma unroll
        for (int r = 0; r < 4; r++){
            buf0[kq*4 + r][col]           = acc00[r];
            buf0[kq*4 + r][col + 16]      = acc01[r];
            buf0[16 + kq*4 + r][col]      = acc10[r];
            buf0[16 + kq*4 + r][col + 16] = acc11[r];
        }
    } else if (w == 3){
        #pragma unroll
        for (int r = 0; r < 4; r++){
            buf1[kq*4 + r][col]           = acc00[r];
            buf1[kq*4 + r][col + 16]      = acc01[r];
            buf1[16 + kq*4 + r][col]      = acc10[r];
            buf1[16 + kq*4 + r][col + 16] = acc11[r];
        }
    }
    __syncthreads();
    if (w == 0){
        #pragma unroll
        for (int r = 0; r < 4; r++){
            acc00[r] += buf0[kq*4 + r][col];
            acc01[r] += buf0[kq*4 + r][col + 16];
            acc10[r] += buf0[16 + kq*4 + r][col];
            acc11[r] += buf0[16 + kq*4 + r][col + 16];
        }
    } else if (w == 1){
        #pragma unroll
        for (int r = 0; r < 4; r++){
            acc00[r] += buf1[kq*4 + r][col];
            acc01[r] += buf1[kq*4 + r][col + 16];
            acc10[r] += buf1[16 + kq*4 + r][col];
            acc11[r] += buf1[16 + kq*4 + r][col + 16];
        }
    }
    __syncthreads();
    if (w == 1){
        #pragma unroll
        for (int r = 0; r < 4; r++){
            buf1[kq*4 + r][col]           = acc00[r];
            buf1[kq*4 + r][col + 16]      = acc01[r];
            buf1[16 + kq*4 + r][col]      = acc10[r];
            buf1[16 + kq*4 + r][col + 16] = acc11[r];
        }
    }
    __syncthreads();
    if (w == 0){
        #pragma unroll
        for (int r = 0; r < 4; r++){
            buf0[kq*4 + r][col]           = acc00[r] + buf1[kq*4 + r][col];
            buf0[kq*4 + r][col + 16]      = acc01[r] + buf1[kq*4 + r][col + 16];
            buf0[16 + kq*4 + r][col]      = acc10[r] + buf1[16 + kq*4 + r][col];
            buf0[16 + kq*4 + r][col + 16] = acc11[r] + buf1[16 + kq*4 + r][col + 16];
        }
    }
    __syncthreads();

    // epilogue: 32 pts x 32 ch; thread t handles 4 elems
    int pt = tid >> 3, c0 = (tid & 7) * 4;
    size_t g = (size_t)(blockIdx.x * 32 + pt) * 32 + c0;
    bf16x4 rh = *(const bf16x4*)(fh + g);
    bf16x4 rl = *(const bf16x4*)(fl + g);
    bf16x4 oh4, ol4;
    if (MODE == 0){
        #pragma unroll
        for (int j = 0; j < 4; j++){
            float v = buf0[pt][c0 + j] + (float)rh[j] + (float)rl[j];
            __bf16 hi = (__bf16)v;
            oh4[j] = hi;
            ol4[j] = (__bf16)(v - (float)hi);
        }
    } else {
        bf16x4 sh = *(const bf16x4*)(r2h + g);
        bf16x4 sl = *(const bf16x4*)(r2l + g);
        #pragma unroll
        for (int j = 0; j < 4; j++){
            float v = buf0[pt][c0 + j] + (float)rh[j] + (float)rl[j]
                                       + (float)sh[j] + (float)sl[j];
            __bf16 hi = (__bf16)v;
            oh4[j] = hi;
            ol4[j] = (__bf16)(v - (float)hi);
        }
    }
    *(bf16x4*)(outh + g) = oh4;
    *(bf16x4*)(outl + g) = ol4;
}

// mlp2: out[m,128] = b2 + sum_kc v_kc[m,32] @ w2[kc] (3-term hi/lo MFMA).
// Block = 32 pts x 4 waves (wave w = out-slice w*32). K = 8 scales x 32.
__global__ __launch_bounds__(256)
void mlp2_kernel(const __bf16* __restrict__ vplanes,
                 const __bf16* __restrict__ w2th, const __bf16* __restrict__ w2tl,
                 const float* __restrict__ b2, float* __restrict__ out)
{
    __shared__ float vsh[32][132];
    int tid  = threadIdx.x;
    int lane = tid & 63, w = tid >> 6;
    int col  = lane & 15, kq = lane >> 4;
    int ptA  = blockIdx.x * 32 + col, ptB = ptA + 16;
    const int fragoff = kq * 8;

    f32x4 acc00 = {0,0,0,0}, acc01 = {0,0,0,0}, acc10 = {0,0,0,0}, acc11 = {0,0,0,0};

    #pragma unroll 1
    for (int kc = 0; kc < 8; kc++){
        const __bf16* fh = vplanes + (size_t)kc * 8388608;   // elements
        const __bf16* fl = fh + 4194304;
        bf16x8 a0h = *(const bf16x8*)(fh + (size_t)ptA*32 + fragoff);
        bf16x8 a0l = *(const bf16x8*)(fl + (size_t)ptA*32 + fragoff);
        bf16x8 a1h = *(const bf16x8*)(fh + (size_t)ptB*32 + fragoff);
        bf16x8 a1l = *(const bf16x8*)(fl + (size_t)ptB*32 + fragoff);

        const __bf16* wb = w2th + (size_t)kc*4096 + (w*32 + col)*32 + fragoff;
        const __bf16* wc = w2tl + (size_t)kc*4096 + (w*32 + col)*32 + fragoff;
        bf16x8 b0h = *(const bf16x8*)(wb);
        bf16x8 b1h = *(const bf16x8*)(wb + 512);    // +16 cols * 32
        bf16x8 b0l = *(const bf16x8*)(wc);
        bf16x8 b1l = *(const bf16x8*)(wc + 512);

        acc00 = __builtin_amdgcn_mfma_f32_16x16x32_bf16(a0h, b0h, acc00, 0,0,0);
        acc00 = __builtin_amdgcn_mfma_f32_16x16x32_bf16(a0h, b0l, acc00, 0,0,0);
        acc00 = __builtin_amdgcn_mfma_f32_16x16x32_bf16(a0l, b0h, acc00, 0,0,0);
        acc01 = __builtin_amdgcn_mfma_f32_16x16x32_bf16(a0h, b1h, acc01, 0,0,0);
        acc01 = __builtin_amdgcn_mfma_f32_16x16x32_bf16(a0h, b1l, acc01, 0,0,0);
        acc01 = __builtin_amdgcn_mfma_f32_16x16x32_bf16(a0l, b1h, acc01, 0,0,0);
        acc10 = __builtin_amdgcn_mfma_f32_16x16x32_bf16(a1h, b0h, acc10, 0,0,0);
        acc10 = __builtin_amdgcn_mfma_f32_16x16x32_bf16(a1h, b0l, acc10, 0,0,0);
        acc10 = __builtin_amdgcn_mfma_f32_16x16x32_bf16(a1l, b0h, acc10, 0,0,0);
        acc11 = __builtin_amdgcn_mfma_f32_16x16x32_bf16(a1h, b1h, acc11, 0,0,0);
        acc11 = __builtin_amdgcn_mfma_f32_16x16x32_bf16(a1h, b1l, acc11, 0,0,0);
        acc11 = __builtin_amdgcn_mfma_f32_16x16x32_bf16(a1l, b1h, acc11, 0,0,0);
    }

    // stage 32x128 tile (+b2) then coalesced f32 store
    #pragma unroll
    for (int r = 0; r < 4; r++){
        vsh[kq*4 + r][w*32 + col]           = acc00[r] + b2[w*32 + col];
        vsh[kq*4 + r][w*32 + col + 16]      = acc01[r] + b2[w*32 + col + 16];
        vsh[16 + kq*4 + r][w*32 + col]      = acc10[r] + b2[w*32 + col];
        vsh[16 + kq*4 + r][w*32 + col + 16] = acc11[r] + b2[w*32 + col + 16];
    }
    __syncthreads();

    int pt = tid >> 3, c0 = (tid & 7) * 16;
    float* obase = out + (size_t)(blockIdx.x * 32 + pt) * 128 + c0;
    #pragma unroll
    for (int q = 0; q < 4; q++)
        ((float4*)obase)[q] = make_float4(vsh[pt][c0 + q*4 + 0], vsh[pt][c0 + q*4 + 1],
                                          vsh[pt][c0 + q*4 + 2], vsh[pt][c0 + q*4 + 3]);
}

// ================================================================ FALLBACK PATH (round-9, verbatim)
// MODE 0: h1 planes = conv(f) + f
// MODE 1: out += (conv(f) + f + h0) @ w2i
// MODE 2: out  = b2 + (conv(f) + f + h0) @ w2i  (first scale)
template<int MODE>
__global__ __launch_bounds__(256)
void conv_mfma_kernel(const __bf16* __restrict__ fh, const __bf16* __restrict__ fl,
                      const __bf16* __restrict__ wth, const __bf16* __restrict__ wtl,
                      const float* __restrict__ bias, const int* __restrict__ nbr,
                      const __bf16* __restrict__ r2h, const __bf16* __restrict__ r2l,
                      const float* __restrict__ w2i, const float* __restrict__ b2,
                      __bf16* __restrict__ outh, __bf16* __restrict__ outl,
                      float* __restrict__ out)
{
    __shared__ float vsh[64][33];
    int tid  = threadIdx.x;
    int lane = tid & 63, wid = tid >> 6;
    int pair = wid >> 1;
    int half = wid & 1;
    int col  = lane & 15, kq = lane >> 4;
    int m0   = blockIdx.x * 64 + pair * 32;
    int ptA  = m0 + col, ptB = ptA + 16;
    const int fragoff = kq * 8;

    f32x4 acc00, acc01, acc10, acc11;
    if (half == 0){
        float bv0 = bias[col], bv1 = bias[col + 16];
        acc00 = (f32x4){bv0,bv0,bv0,bv0}; acc01 = (f32x4){bv1,bv1,bv1,bv1};
        acc10 = (f32x4){bv0,bv0,bv0,bv0}; acc11 = (f32x4){bv1,bv1,bv1,bv1};
    } else {
        acc00 = (f32x4){0,0,0,0}; acc01 = (f32x4){0,0,0,0};
        acc10 = (f32x4){0,0,0,0}; acc11 = (f32x4){0,0,0,0};
    }

    int k0 = half ? 14 : 0;
    int k1 = half ? 27 : 14;
    #pragma unroll 1
    for (int k = k0; k < k1; k++){
        int nb0 = nbr[k * MTOT + ptA];
        int nb1 = nbr[k * MTOT + ptB];
        size_t o0 = (size_t)(nb0 < 0 ? 0 : nb0) * 32 + fragoff;
        size_t o1 = (size_t)(nb1 < 0 ? 0 : nb1) * 32 + fragoff;
        bf16x8 a0h = *(const bf16x8*)(fh + o0);
        bf16x8 a0l = *(const bf16x8*)(fl + o0);
        bf16x8 a1h = *(const bf16x8*)(fh + o1);
        bf16x8 a1l = *(const bf16x8*)(fl + o1);
        bf16x8 z = {};
        if (nb0 < 0){ a0h = z; a0l = z; }
        if (nb1 < 0){ a1h = z; a1l = z; }

        const __bf16* wb = wth + (size_t)k*1024 + col*32 + fragoff;
        const __bf16* wc = wtl + (size_t)k*1024 + col*32 + fragoff;
        bf16x8 b0h = *(const bf16x8*)(wb);
        bf16x8 b1h = *(const bf16x8*)(wb + 512);
        bf16x8 b0l = *(const bf16x8*)(wc);
        bf16x8 b1l = *(const bf16x8*)(wc + 512);

        acc00 = __builtin_amdgcn_mfma_f32_16x16x32_bf16(a0h, b0h, acc00, 0,0,0);
        acc00 = __builtin_amdgcn_mfma_f32_16x16x32_bf16(a0h, b0l, acc00, 0,0,0);
        acc00 = __builtin_amdgcn_mfma_f32_16x16x32_bf16(a0l, b0h, acc00, 0,0,0);
        acc01 = __builtin_amdgcn_mfma_f32_16x16x32_bf16(a0h, b1h, acc01, 0,0,0);
        acc01 = __builtin_amdgcn_mfma_f32_16x16x32_bf16(a0h, b1l, acc01, 0,0,0);
        acc01 = __builtin_amdgcn_mfma_f32_16x16x32_bf16(a0l, b1h, acc01, 0,0,0);
        acc10 = __builtin_amdgcn_mfma_f32_16x16x32_bf16(a1h, b0h, acc10, 0,0,0);
        acc10 = __builtin_amdgcn_mfma_f32_16x16x32_bf16(a1h, b0l, acc10, 0,0,0);
        acc10 = __builtin_amdgcn_mfma_f32_16x16x32_bf16(a1l, b0h, acc10, 0,0,0);
        acc11 = __builtin_amdgcn_mfma_f32_16x16x32_bf16(a1h, b1h, acc11, 0,0,0);
        acc11 = __builtin_amdgcn_mfma_f32_16x16x32_bf16(a1h, b1l, acc11, 0,0,0);
        acc11 = __builtin_amdgcn_mfma_f32_16x16x32_bf16(a1l, b1h, acc11, 0,0,0);
    }

    if (half == 1){
        #pragma unroll
        for (int r = 0; r < 4; r++){
            vsh[pair*32 + kq*4 + r][col]           = acc00[r];
            vsh[pair*32 + kq*4 + r][col + 16]      = acc01[r];
            vsh[pair*32 + 16 + kq*4 + r][col]      = acc10[r];
            vsh[pair*32 + 16 + kq*4 + r][col + 16] = acc11[r];
        }
    }
    __syncthreads();
    if (half == 0){
        #pragma unroll
        for (int r = 0; r < 4; r++){
            vsh[pair*32 + kq*4 + r][col]           += acc00[r];
            vsh[pair*32 + kq*4 + r][col + 16]      += acc01[r];
            vsh[pair*32 + 16 + kq*4 + r][col]      += acc10[r];
            vsh[pair*32 + 16 + kq*4 + r][col + 16] += acc11[r];
        }
    }
    __syncthreads();

    if (MODE == 0){
        int eidx = tid * 8;
        int pt = eidx >> 5, c0 = eidx & 31;
        size_t g = (size_t)blockIdx.x * 2048 + eidx;
        bf16x8 rh = *(const bf16x8*)(fh + g);
        bf16x8 rl = *(const bf16x8*)(fl + g);
        bf16x8 oh8, ol8;
        #pragma unroll
        for (int j = 0; j < 8; j++){
            float v = vsh[pt][c0 + j] + (float)rh[j] + (float)rl[j];
            __bf16 hi = (__bf16)v;
            oh8[j] = hi;
            ol8[j] = (__bf16)(v - (float)hi);
        }
        *(bf16x8*)(outh + g) = oh8;
        *(bf16x8*)(outl + g) = ol8;
    } else {
        int eidx = tid * 8;
        int pt = eidx >> 5, c0 = eidx & 31;
        size_t g = (size_t)blockIdx.x * 2048 + eidx;
        bf16x8 rh = *(const bf16x8*)(fh + g);
        bf16x8 rl = *(const bf16x8*)(fl + g);
        bf16x8 sh = *(const bf16x8*)(r2h + g);
        bf16x8 sl = *(const bf16x8*)(r2l + g);
        #pragma unroll
        for (int j = 0; j < 8; j++)
            vsh[pt][c0 + j] += (float)rh[j] + (float)rl[j] + (float)sh[j] + (float)sl[j];
        __syncthreads();

        int pm = tid & 63;
        int tg = __builtin_amdgcn_readfirstlane(tid >> 6);
        size_t m = (size_t)blockIdx.x * 64 + pm;
        float o32[32];
        float* obase = out + m*128 + tg*32;
        if (MODE == 2){
            #pragma unroll
            for (int o = 0; o < 32; o++) o32[o] = b2[tg*32 + o];
        } else {
            #pragma unroll
            for (int q = 0; q < 8; q++){
                float4 t4 = ((const float4*)obase)[q];
                o32[q*4+0] = t4.x; o32[q*4+1] = t4.y; o32[q*4+2] = t4.z; o32[q*4+3] = t4.w;
            }
        }
        #pragma unroll
        for (int c = 0; c < 32; c++){
            float vc = vsh[pm][c];
            const float* w2r = w2i + c*128 + tg*32;
            #pragma unroll
            for (int o = 0; o < 32; o++) o32[o] += vc * w2r[o];
        }
        #pragma unroll
        for (int q = 0; q < 8; q++)
            ((float4*)obase)[q] = make_float4(o32[q*4+0], o32[q*4+1], o32[q*4+2], o32[q*4+3]);
    }
}

// ---------------------------------------------------------------- launch
extern "C" void kernel_launch(void* const* d_in, const int* in_sizes, int n_in,
                              void* d_out, int out_size, void* d_ws, size_t ws_size,
                              hipStream_t stream)
{
    static const int want[9] = {393216, 96, 32, 8192, 256, 442368, 512, 32768, 128};
    const void* bound[9];
    for (int i = 0; i < 9; i++) bound[i] = d_in[i];
    if (n_in == 9){
        for (int i = 0; i < 9; i++)
            for (int j = 0; j < 9; j++)
                if (in_sizes[j] == want[i]) { bound[i] = d_in[j]; break; }
    }
    const float* p      = (const float*)bound[0];
    const float* w1     = (const float*)bound[1];
    const float* b1     = (const float*)bound[2];
    const float* w_mlp  = (const float*)bound[3];
    const float* b_mlp  = (const float*)bound[4];
    const float* w_conv = (const float*)bound[5];
    const float* b_conv = (const float*)bound[6];
    const float* w2     = (const float*)bound[7];
    const float* b2     = (const float*)bound[8];
    float* out = (float*)d_out;

    // Workspace layout. Base (~50 MB) shared by both paths; big path adds 134 MB
    // of per-scale v planes at 0x3000000 and defers mlp2 to one MFMA GEMM.
    char* ws = (char*)d_ws;
    __bf16* h0h  = (__bf16*)(ws);
    __bf16* h0l  = (__bf16*)(ws + 8388608);
    __bf16* h1h  = (__bf16*)(ws + 16777216);
    int*    vgrid= (int*)   (ws + 16777216);            // alias of h1h
    __bf16* h1l  = (__bf16*)(ws + 25165824);
    int*    gcbuf= (int*)   (ws + 25165824);            // alias of h1l
    int*    nbr  = (int*)   (ws + 33554432);            // 14,155,776 B
    __bf16* wth  = (__bf16*)(ws + 47710208);            // 884,736 B
    __bf16* wtl  = (__bf16*)(ws + 48594944);            // 884,736 B
    __bf16* w2th = (__bf16*)(ws + 49479680);            // 65,536 B
    __bf16* w2tl = (__bf16*)(ws + 49545216);            // 65,536 B
    float*  pmin = (float*) (ws + 49610752);
    __bf16* vpl  = (__bf16*)(ws + 50331648);            // 8 x 16 MiB (big path only)

    const bool big = (ws_size >= 184549376ULL);          // 0x3000000 + 8*16 MiB

    static const double GS[8] = {0.01, 0.02, 0.04, 0.08, 0.16, 0.32, 0.64, 1.28};
    static const int    DS[8] = {101, 51, 26, 14, 8, 5, 3, 2};   // ceil(1/g)+1

    pmin_init_kernel<<<1, 64, 0, stream>>>(pmin);
    pmin_kernel<<<dim3(64, 2), 256, 0, stream>>>(p, pmin);
    wcv_kernel<<<1728, 256, 0, stream>>>(w_conv, wth, wtl);
    if (big) w2t_kernel<<<128, 256, 0, stream>>>(w2, w2th, w2tl);

    for (int i = 0; i < 8; i++){
        int D = DS[i]; double gd = GS[i];
        int ncell = D * D * D;
        hipMemsetAsync(vgrid, 0xFF, (size_t)2*ncell*sizeof(int), stream);
        if (ncell <= 2744)
            scatter_kernel<1><<<MTOT/256, 256, ncell*sizeof(int), stream>>>(p, pmin, vgrid, gcbuf, gd, D);
        else
            scatter_kernel<0><<<MTOT/256, 256, 0, stream>>>(p, pmin, vgrid, gcbuf, gd, D);
        nbr_kernel<<<MTOT/256, 256, 0, stream>>>(gcbuf, vgrid, nbr, D);
        mlp_scale_kernel<<<(MTOT*32)/256, 256, 0, stream>>>(p, w1, b1, w_mlp + i*1024, b_mlp + i*32, h0h, h0l);

        if (big){
            conv4_kernel<0><<<MTOT/32, 256, 0, stream>>>(
                h0h, h0l, wth + (size_t)(2*i)*27648, wtl + (size_t)(2*i)*27648,
                b_conv + (2*i)*32, nbr, nullptr, nullptr, h1h, h1l);
            conv4_kernel<1><<<MTOT/32, 256, 0, stream>>>(
                h1h, h1l, wth + (size_t)(2*i+1)*27648, wtl + (size_t)(2*i+1)*27648,
                b_conv + (2*i+1)*32, nbr, h0h, h0l,
                vpl + (size_t)i*8388608, vpl + (size_t)i*8388608 + 4194304);
        } else {
            conv_mfma_kernel<0><<<MTOT/64, 256, 0, stream>>>(
                h0h, h0l, wth + (size_t)(2*i)*27648, wtl + (size_t)(2*i)*27648,
                b_conv + (2*i)*32, nbr, nullptr, nullptr, nullptr, nullptr,
                h1h, h1l, nullptr);
            if (i == 0)
                conv_mfma_kernel<2><<<MTOT/64, 256, 0, stream>>>(
                    h1h, h1l, wth + (size_t)(2*i+1)*27648, wtl + (size_t)(2*i+1)*27648,
                    b_conv + (2*i+1)*32, nbr, h0h, h0l, w2 + i*32*128, b2,
                    nullptr, nullptr, out);
            else
                conv_mfma_kernel<1><<<MTOT/64, 256, 0, stream>>>(
                    h1h, h1l, wth + (size_t)(2*i+1)*27648, wtl + (size_t)(2*i+1)*27648,
                    b_conv + (2*i+1)*32, nbr, h0h, h0l, w2 + i*32*128, nullptr,
                    nullptr, nullptr, out);
        }
    }
    if (big)
        mlp2_kernel<<<MTOT/32, 256, 0, stream>>>(vpl, w2th, w2tl, b2, out);
}